// Round 4
// baseline (503.678 us; speedup 1.0000x reference)
//
#include <hip/hip_runtime.h>
#include <hip/hip_fp16.h>
#include <hip/hip_cooperative_groups.h>

namespace cg = cooperative_groups;

#define N_NODES 100000
#define N_EDGES 1600000
#define MSG 16
#define HID 16
#define NC 32
#define PREP_N 800000       // N*HID/2 packed half2 words == N*MSG/2 m2 words
#define A2_WORDS 1024       // NT*MSG*HID/2 packed half2 words (4 KB)

// Fine-binned two-pass message reduction:
#define BINW 128            // nodes per bin (dst >> 7)
#define NBIN 782            // ceil(100000/128)
#define NBIN_PAD 1024       // padded for scan / binary search
#define BCAP 2560           // per-bin capacity (mean 2048, sigma 45 -> +11 sigma)
#define CHUNK 4096          // edges per block in the binning pass
#define NCHUNK 391          // ceil(N_EDGES / CHUNK)
#define ACCW 17             // padded LDS accumulator stride (bank spread)

typedef _Float16 v2h __attribute__((ext_vector_type(2)));

union H2U {
    v2h h;
    unsigned int u;
};

__device__ __forceinline__ float dot2acc(unsigned int a, unsigned int b, float acc) {
    H2U x, y;
    x.u = a; y.u = b;
#if __has_builtin(__builtin_amdgcn_fdot2)
    return __builtin_amdgcn_fdot2(x.h, y.h, acc, false);
#else
    return acc + (float)x.h[0] * (float)y.h[0] + (float)x.h[1] * (float)y.h[1];
#endif
}

__device__ __forceinline__ float fast_sigmoid(float x) {
    return 1.f / (1.f + __expf(-x));
}
__device__ __forceinline__ float fast_tanh(float x) {
    return 2.f / (1.f + __expf(-2.f * x)) - 1.f;
}

// ---------------------------------------------------------------------------
// Shared-memory layouts. BinShared = 53 KB (fits 3 blocks/CU of 160 KB).
// ---------------------------------------------------------------------------
struct BinShared {
    unsigned int   recs[CHUNK];      // 16 KB
    unsigned int   sorted[CHUNK];    // 16 KB
    unsigned short binof[CHUNK];     // 8 KB
    unsigned int   excl[NBIN_PAD];   // 4 KB: histogram, then excl prefix in place
    unsigned int   base[NBIN_PAD];   // 4 KB: global segment base per bin
    unsigned int   cursor[NBIN_PAD]; // 4 KB: LDS scatter cursor
    unsigned int   tsum[256];        // 1 KB: scan scratch
};
union FusedShared {
    BinShared a;
    float acc[BINW * ACCW];          // 8.7 KB pull accumulator
};

// ---------------------------------------------------------------------------
// Phase: prep (grid-stride). feat f32 -> packed fp16 mirror; pack edge_table;
// zero bincnt (binned path) and/or m2 (fallback scatter path).
// ---------------------------------------------------------------------------
__device__ __forceinline__ void phase_prep(
    int gtid, int gsz,
    const float* __restrict__ feat,
    const float* __restrict__ edge_table,
    unsigned int* __restrict__ feat16,
    unsigned int* __restrict__ A2,
    unsigned int* __restrict__ bincnt,   // nullable
    unsigned int* __restrict__ m2z) {    // nullable
    for (int i = gtid; i < PREP_N; i += gsz) {
        float2 f = reinterpret_cast<const float2*>(feat)[i];
        H2U p;
        p.h[0] = (_Float16)f.x;
        p.h[1] = (_Float16)f.y;
        feat16[i] = p.u;
        if (m2z) m2z[i] = 0u;
    }
    for (int i = gtid; i < A2_WORDS; i += gsz) {
        float2 f = reinterpret_cast<const float2*>(edge_table)[i];
        H2U p;
        p.h[0] = (_Float16)f.x;
        p.h[1] = (_Float16)f.y;
        A2[i] = p.u;
    }
    if (bincnt)
        for (int i = gtid; i < NBIN_PAD; i += gsz) bincnt[i] = 0u;
}

// ---------------------------------------------------------------------------
// Phase: binning (one CHUNK of 4096 edges per call). LDS counting sort into
// 782 fine bins; per-bin global reservation; coalesced run flush.
// Record = [dstlo:7][etype:3][src:17].
// ---------------------------------------------------------------------------
__device__ __forceinline__ void binA_chunk(
    int chunk, int tid,
    const int* __restrict__ src,
    const int* __restrict__ dst,
    const int* __restrict__ etype,
    unsigned int* __restrict__ bincnt,
    unsigned int* __restrict__ binbuf,
    BinShared& sh) {
    int e0 = chunk * CHUNK;
    int total = N_EDGES - e0;
    if (total > CHUNK) total = CHUNK;

    for (int i = tid; i < NBIN_PAD; i += 256) sh.excl[i] = 0u;
    __syncthreads();

    // 1) read edges, build records, LDS histogram
    for (int i = tid; i < total; i += 256) {
        int g = e0 + i;
        unsigned int d = (unsigned int)dst[g];
        unsigned int s = (unsigned int)src[g];
        unsigned int t = (unsigned int)etype[g];
        unsigned int bin = d >> 7;
        sh.recs[i] = ((d & 127u) << 20) | (t << 17) | s;
        sh.binof[i] = (unsigned short)bin;
        atomicAdd(&sh.excl[bin], 1u);
    }
    __syncthreads();

    // 2) blocked exclusive scan over 1024 counters (4 per thread)
    unsigned int c0 = sh.excl[4 * tid], c1 = sh.excl[4 * tid + 1],
                 c2 = sh.excl[4 * tid + 2], c3 = sh.excl[4 * tid + 3];
    unsigned int s4 = c0 + c1 + c2 + c3;
    sh.tsum[tid] = s4;
    __syncthreads();
    for (int off = 1; off < 256; off <<= 1) {
        unsigned int v = sh.tsum[tid] + (tid >= off ? sh.tsum[tid - off] : 0u);
        __syncthreads();
        sh.tsum[tid] = v;
        __syncthreads();
    }
    unsigned int e = sh.tsum[tid] - s4;   // exclusive block offset
    unsigned int e0v = e, e1v = e + c0, e2v = e1v + c1, e3v = e2v + c2;
    sh.excl[4 * tid]     = e0v;
    sh.excl[4 * tid + 1] = e1v;
    sh.excl[4 * tid + 2] = e2v;
    sh.excl[4 * tid + 3] = e3v;
    sh.cursor[4 * tid]     = e0v;
    sh.cursor[4 * tid + 1] = e1v;
    sh.cursor[4 * tid + 2] = e2v;
    sh.cursor[4 * tid + 3] = e3v;
    // 3) reserve global segments (one atomic per touched bin)
    if (c0) sh.base[4 * tid]     = atomicAdd(&bincnt[4 * tid],     c0);
    if (c1) sh.base[4 * tid + 1] = atomicAdd(&bincnt[4 * tid + 1], c1);
    if (c2) sh.base[4 * tid + 2] = atomicAdd(&bincnt[4 * tid + 2], c2);
    if (c3) sh.base[4 * tid + 3] = atomicAdd(&bincnt[4 * tid + 3], c3);
    __syncthreads();

    // 4) scatter into bin-sorted LDS order
    for (int i = tid; i < total; i += 256) {
        unsigned int b = sh.binof[i];
        unsigned int p = atomicAdd(&sh.cursor[b], 1u);
        sh.sorted[p] = sh.recs[i];
    }
    __syncthreads();

    // 5) coalesced flush; position -> bin via binary search on excl
    for (int p = tid; p < total; p += 256) {
        int lo = 0, hi = NBIN_PAD - 1;
        while (lo < hi) {
            int mid = (lo + hi + 1) >> 1;
            if (sh.excl[mid] <= (unsigned int)p) lo = mid; else hi = mid - 1;
        }
        unsigned int off = (unsigned int)p - sh.excl[lo];
        unsigned int gpos = sh.base[lo] + off;
        if (gpos < BCAP)
            binbuf[(size_t)lo * BCAP + gpos] = sh.sorted[p];
    }
    __syncthreads();   // LDS reused by next chunk / next phase
}

// ---------------------------------------------------------------------------
// Phase: pull (one 128-node bin per call). 8 lanes per record, 4-deep ILP.
// f32 accumulation in block-exclusive LDS; zero global atomics; coalesced
// half2 flush of m2.
// ---------------------------------------------------------------------------
__device__ __forceinline__ void pull_bin(
    int b, int tid,
    const unsigned int* __restrict__ bincnt,
    const unsigned int* __restrict__ binbuf,
    const unsigned int* __restrict__ feat16,
    const unsigned int* __restrict__ A2,
    unsigned int* __restrict__ m2,
    float* acc) {
    for (int i = tid; i < BINW * ACCW; i += 256) acc[i] = 0.f;
    __syncthreads();

    int cnt = (int)bincnt[b];
    if (cnt > BCAP) cnt = BCAP;
    const unsigned int* seg = binbuf + (size_t)b * BCAP;
    int g = tid >> 3, c = tid & 7;

    for (int i = g; i < cnt; i += 128) {   // 32 groups x 4 records in flight
        unsigned int rv[4];
        bool val[4];
        #pragma unroll
        for (int k = 0; k < 4; ++k) {
            int idx = i + 32 * k;
            val[k] = idx < cnt;
            rv[k] = val[k] ? seg[idx] : 0u;
        }
        uint4 h0[4], h1[4], a0[4], a1[4], a2v[4], a3[4];
        #pragma unroll
        for (int k = 0; k < 4; ++k) {
            int s = (int)(rv[k] & 0x1FFFFu);
            int t = (int)((rv[k] >> 17) & 7u);
            const uint4* hp = reinterpret_cast<const uint4*>(feat16 + (size_t)s * 8);
            h0[k] = hp[0];
            h1[k] = hp[1];
            const uint4* ap = reinterpret_cast<const uint4*>(A2 + t * 128 + c * 16);
            a0[k] = ap[0]; a1[k] = ap[1]; a2v[k] = ap[2]; a3[k] = ap[3];
        }
        #pragma unroll
        for (int k = 0; k < 4; ++k) {
            float r0 = 0.f, r1 = 0.f;
            r0 = dot2acc(h0[k].x, a0[k].x, r0); r0 = dot2acc(h0[k].y, a0[k].y, r0);
            r0 = dot2acc(h0[k].z, a0[k].z, r0); r0 = dot2acc(h0[k].w, a0[k].w, r0);
            r0 = dot2acc(h1[k].x, a1[k].x, r0); r0 = dot2acc(h1[k].y, a1[k].y, r0);
            r0 = dot2acc(h1[k].z, a1[k].z, r0); r0 = dot2acc(h1[k].w, a1[k].w, r0);
            r1 = dot2acc(h0[k].x, a2v[k].x, r1); r1 = dot2acc(h0[k].y, a2v[k].y, r1);
            r1 = dot2acc(h0[k].z, a2v[k].z, r1); r1 = dot2acc(h0[k].w, a2v[k].w, r1);
            r1 = dot2acc(h1[k].x, a3[k].x, r1); r1 = dot2acc(h1[k].y, a3[k].y, r1);
            r1 = dot2acc(h1[k].z, a3[k].z, r1); r1 = dot2acc(h1[k].w, a3[k].w, r1);
            if (val[k]) {
                int dlo = (int)(rv[k] >> 20);
                atomicAdd(&acc[dlo * ACCW + 2 * c],     r0);
                atomicAdd(&acc[dlo * ACCW + 2 * c + 1], r1);
            }
        }
    }
    __syncthreads();

    int n0 = b * BINW;
    for (int idx = tid; idx < BINW * 8; idx += 256) {
        int node = idx >> 3, w = idx & 7, n = n0 + node;
        if (n < N_NODES) {
            H2U p;
            p.h[0] = (_Float16)acc[node * ACCW + 2 * w];
            p.h[1] = (_Float16)acc[node * ACCW + 2 * w + 1];
            m2[(size_t)n * 8 + w] = p.u;
        }
    }
    __syncthreads();   // acc reused by next bin
}

// ---------------------------------------------------------------------------
// Phase: node (grid-stride). GRU cell + output projection. (Proven.)
// ---------------------------------------------------------------------------
__device__ __forceinline__ void phase_node(
    int gtid, int gsz,
    const float* __restrict__ feat,
    const unsigned int* __restrict__ m2,
    const float* __restrict__ W_ih,
    const float* __restrict__ W_hh,
    const float* __restrict__ b_ih,
    const float* __restrict__ b_hh,
    const float* __restrict__ W_out,
    const float* __restrict__ b_out,
    float* __restrict__ out) {
    for (int n = gtid; n < N_NODES; n += gsz) {
        float mv[MSG], h[HID];
        {
            const uint4* mu = reinterpret_cast<const uint4*>(m2 + (size_t)n * 8);
            uint4 a = mu[0], b = mu[1];
            unsigned int w[8] = {a.x, a.y, a.z, a.w, b.x, b.y, b.z, b.w};
            #pragma unroll
            for (int i = 0; i < 8; ++i) {
                H2U hh;
                hh.u = w[i];
                mv[2 * i]     = (float)hh.h[0];
                mv[2 * i + 1] = (float)hh.h[1];
            }
            const float4* f4 = reinterpret_cast<const float4*>(feat + (size_t)n * HID);
            #pragma unroll
            for (int q = 0; q < 4; ++q) {
                float4 v = f4[q];
                h[q * 4 + 0] = v.x; h[q * 4 + 1] = v.y;
                h[q * 4 + 2] = v.z; h[q * 4 + 3] = v.w;
            }
        }

        float srz[2 * HID];
        for (int g = 0; g < 2 * HID; ++g) {
            float ai = 0.f, ah = 0.f;
            const float* wi = W_ih + g * MSG;
            const float* wh = W_hh + g * HID;
            #pragma unroll
            for (int k = 0; k < HID; ++k) {
                ai += wi[k] * mv[k];
                ah += wh[k] * h[k];
            }
            srz[g] = ai + ah + b_ih[g] + b_hh[g];
        }
        float i_n[HID], h_n[HID];
        #pragma unroll
        for (int j = 0; j < HID; ++j) {
            int g = 2 * HID + j;
            float ai = b_ih[g], ah = b_hh[g];
            const float* wi = W_ih + g * MSG;
            const float* wh = W_hh + g * HID;
            #pragma unroll
            for (int k = 0; k < HID; ++k) {
                ai += wi[k] * mv[k];
                ah += wh[k] * h[k];
            }
            i_n[j] = ai;
            h_n[j] = ah;
        }

        float hn[HID];
        #pragma unroll
        for (int j = 0; j < HID; ++j) {
            float r = fast_sigmoid(srz[j]);
            float z = fast_sigmoid(srz[HID + j]);
            float nn = fast_tanh(i_n[j] + r * h_n[j]);
            hn[j] = (1.f - z) * nn + z * h[j];
        }

        float4* op = reinterpret_cast<float4*>(out + (size_t)n * NC);
        #pragma unroll
        for (int c4 = 0; c4 < NC / 4; ++c4) {
            float4 o;
            float* oo = &o.x;
            #pragma unroll
            for (int cc = 0; cc < 4; ++cc) {
                int c = c4 * 4 + cc;
                float acc2 = b_out[c];
                const float* wo = W_out + c * HID;
                #pragma unroll
                for (int k = 0; k < HID; ++k) acc2 += wo[k] * hn[k];
                oo[cc] = acc2;
            }
            op[c4] = o;
        }
    }
}

// ---------------------------------------------------------------------------
// Fused cooperative kernel: prep -> binA -> pull -> node, one dispatch.
// Eliminates ~30 us per inter-dispatch gap (round-0/2/3 cross evidence).
// ---------------------------------------------------------------------------
__global__ __launch_bounds__(256) void ggnn_fused(
    const float* feat, const int* src, const int* dst, const int* etype,
    const float* edge_table,
    const float* W_ih, const float* W_hh, const float* b_ih, const float* b_hh,
    const float* W_out, const float* b_out,
    float* out, unsigned int* m2, unsigned int* feat16, unsigned int* A2,
    unsigned int* bincnt, unsigned int* binbuf) {
    __shared__ FusedShared sh;
    cg::grid_group grid = cg::this_grid();
    int tid = threadIdx.x;
    int gtid = blockIdx.x * 256 + tid;
    int gsz = gridDim.x * 256;

    phase_prep(gtid, gsz, feat, edge_table, feat16, A2, bincnt, nullptr);
    __threadfence();
    grid.sync();

    for (int ch = blockIdx.x; ch < NCHUNK; ch += gridDim.x)
        binA_chunk(ch, tid, src, dst, etype, bincnt, binbuf, sh.a);
    __threadfence();
    grid.sync();

    for (int b = blockIdx.x; b < NBIN; b += gridDim.x)
        pull_bin(b, tid, bincnt, binbuf, feat16, A2, m2, sh.acc);
    __threadfence();
    grid.sync();

    phase_node(gtid, gsz, feat, m2, W_ih, W_hh, b_ih, b_hh, W_out, b_out, out);
}

// ---------------------------------------------------------------------------
// Standalone kernels (fallback if cooperative launch unavailable).
// ---------------------------------------------------------------------------
__global__ __launch_bounds__(256) void ggnn_prep_s(
    const float* feat, const float* edge_table,
    unsigned int* feat16, unsigned int* A2,
    unsigned int* bincnt, unsigned int* m2z) {
    phase_prep(blockIdx.x * 256 + threadIdx.x, gridDim.x * 256,
               feat, edge_table, feat16, A2, bincnt, m2z);
}

__global__ __launch_bounds__(256) void ggnn_binA_s(
    const int* src, const int* dst, const int* etype,
    unsigned int* bincnt, unsigned int* binbuf) {
    __shared__ BinShared sh;
    for (int ch = blockIdx.x; ch < NCHUNK; ch += gridDim.x)
        binA_chunk(ch, threadIdx.x, src, dst, etype, bincnt, binbuf, sh);
}

__global__ __launch_bounds__(256) void ggnn_pull_s(
    const unsigned int* bincnt, const unsigned int* binbuf,
    const unsigned int* feat16, const unsigned int* A2, unsigned int* m2) {
    __shared__ float acc[BINW * ACCW];
    for (int b = blockIdx.x; b < NBIN; b += gridDim.x)
        pull_bin(b, threadIdx.x, bincnt, binbuf, feat16, A2, m2, acc);
}

__global__ __launch_bounds__(256) void ggnn_node_s(
    const float* feat, const unsigned int* m2,
    const float* W_ih, const float* W_hh, const float* b_ih, const float* b_hh,
    const float* W_out, const float* b_out, float* out) {
    phase_node(blockIdx.x * 256 + threadIdx.x, gridDim.x * 256,
               feat, m2, W_ih, W_hh, b_ih, b_hh, W_out, b_out, out);
}

// Proven round-0 atomic-scatter edge kernel (tiny-workspace fallback).
__global__ __launch_bounds__(256) void ggnn_edge(
    const int* __restrict__ src,
    const int* __restrict__ dst,
    const int* __restrict__ etype,
    const unsigned int* __restrict__ feat16,
    const unsigned int* __restrict__ A2,
    unsigned int* __restrict__ m2) {
    int tid = blockIdx.x * 256 + threadIdx.x;
    int e = tid >> 3;
    if (e >= N_EDGES) return;
    int c = tid & 7;

    int s = src[e];
    int t = etype[e];
    const uint4* hp = reinterpret_cast<const uint4*>(feat16 + (size_t)s * 8);
    uint4 h0 = hp[0], h1 = hp[1];
    const uint4* ap = reinterpret_cast<const uint4*>(A2 + t * 128 + c * 16);
    uint4 a0 = ap[0], a1 = ap[1], a2 = ap[2], a3 = ap[3];

    float r0 = 0.f, r1 = 0.f;
    r0 = dot2acc(h0.x, a0.x, r0); r0 = dot2acc(h0.y, a0.y, r0);
    r0 = dot2acc(h0.z, a0.z, r0); r0 = dot2acc(h0.w, a0.w, r0);
    r0 = dot2acc(h1.x, a1.x, r0); r0 = dot2acc(h1.y, a1.y, r0);
    r0 = dot2acc(h1.z, a1.z, r0); r0 = dot2acc(h1.w, a1.w, r0);
    r1 = dot2acc(h0.x, a2.x, r1); r1 = dot2acc(h0.y, a2.y, r1);
    r1 = dot2acc(h0.z, a2.z, r1); r1 = dot2acc(h0.w, a2.w, r1);
    r1 = dot2acc(h1.x, a3.x, r1); r1 = dot2acc(h1.y, a3.y, r1);
    r1 = dot2acc(h1.z, a3.z, r1); r1 = dot2acc(h1.w, a3.w, r1);

    int d = dst[e];
    H2U p;
    p.h[0] = (_Float16)r0;
    p.h[1] = (_Float16)r1;
#if __has_builtin(__builtin_amdgcn_global_atomic_fadd_v2f16)
    __builtin_amdgcn_global_atomic_fadd_v2f16(
        reinterpret_cast<v2h*>(m2 + (size_t)d * 8 + c), p.h);
#endif
}

extern "C" void kernel_launch(void* const* d_in, const int* in_sizes, int n_in,
                              void* d_out, int out_size, void* d_ws, size_t ws_size,
                              hipStream_t stream) {
    const float* feat       = (const float*)d_in[0];
    const int*   src        = (const int*)d_in[1];
    const int*   dst        = (const int*)d_in[2];
    const int*   etype      = (const int*)d_in[3];
    const float* edge_table = (const float*)d_in[4];
    const float* W_ih       = (const float*)d_in[5];
    const float* W_hh       = (const float*)d_in[6];
    const float* b_ih       = (const float*)d_in[7];
    const float* b_hh       = (const float*)d_in[8];
    const float* W_out      = (const float*)d_in[9];
    const float* b_out      = (const float*)d_in[10];
    float* out = (float*)d_out;

    // workspace layout (words): m2 [800K], feat16 [800K], A2 [1K],
    // bincnt [1K], binbuf [782*2560 ~ 2.0M]  -> ~14.4 MB total
    unsigned int* m2     = (unsigned int*)d_ws;
    unsigned int* feat16 = m2 + PREP_N;
    unsigned int* A2     = feat16 + PREP_N;
    unsigned int* bincnt = A2 + A2_WORDS;
    unsigned int* binbuf = bincnt + NBIN_PAD;

    size_t need = ((size_t)PREP_N * 2 + A2_WORDS + NBIN_PAD +
                   (size_t)NBIN * BCAP) * sizeof(unsigned int);

    int pblocks = (PREP_N + 255) / 256;                  // 3125
    int nblocks = (N_NODES + 255) / 256;                 // 391

    if (ws_size < need) {
        // Tiny-workspace fallback: proven round-0 atomic-scatter path.
        ggnn_prep_s<<<pblocks, 256, 0, stream>>>(feat, edge_table, feat16, A2,
                                                 nullptr, m2);
        long long ethreads = (long long)N_EDGES * 8;
        int eblocks = (int)((ethreads + 255) / 256);
        ggnn_edge<<<eblocks, 256, 0, stream>>>(src, dst, etype, feat16, A2, m2);
        ggnn_node_s<<<nblocks, 256, 0, stream>>>(feat, m2, W_ih, W_hh, b_ih, b_hh,
                                                 W_out, b_out, out);
        return;
    }

    // One-time occupancy/CU query for the cooperative grid.
    static int coopBlocks = -2;   // -2 = not yet queried, -1 = unavailable
    if (coopBlocks == -2) {
        int maxB = 0;
        hipError_t oe = hipOccupancyMaxActiveBlocksPerMultiprocessor(
            &maxB, ggnn_fused, 256, 0);
        int cus = 256;
        hipDeviceProp_t prop;
        if (hipGetDeviceProperties(&prop, 0) == hipSuccess &&
            prop.multiProcessorCount > 0)
            cus = prop.multiProcessorCount;
        if (oe == hipSuccess && maxB > 0) {
            if (maxB > 4) maxB = 4;
            coopBlocks = maxB * cus;
        } else {
            coopBlocks = -1;
        }
    }

    if (coopBlocks > 0) {
        void* args[] = {
            (void*)&feat, (void*)&src, (void*)&dst, (void*)&etype,
            (void*)&edge_table,
            (void*)&W_ih, (void*)&W_hh, (void*)&b_ih, (void*)&b_hh,
            (void*)&W_out, (void*)&b_out,
            (void*)&out, (void*)&m2, (void*)&feat16, (void*)&A2,
            (void*)&bincnt, (void*)&binbuf
        };
        hipError_t le = hipLaunchCooperativeKernel(
            reinterpret_cast<const void*>(ggnn_fused),
            dim3((unsigned)coopBlocks), dim3(256), args, 0, stream);
        if (le == hipSuccess) return;
        coopBlocks = -1;   // remember failure, fall through
    }

    // Separate-launch binned path.
    ggnn_prep_s<<<pblocks, 256, 0, stream>>>(feat, edge_table, feat16, A2,
                                             bincnt, nullptr);
    ggnn_binA_s<<<NCHUNK, 256, 0, stream>>>(src, dst, etype, bincnt, binbuf);
    ggnn_pull_s<<<NBIN, 256, 0, stream>>>(bincnt, binbuf, feat16, A2, m2);
    ggnn_node_s<<<nblocks, 256, 0, stream>>>(feat, m2, W_ih, W_hh, b_ih, b_hh,
                                             W_out, b_out, out);
}

// Round 5
// 243.343 us; speedup vs baseline: 2.0698x; 2.0698x over previous
//
#include <hip/hip_runtime.h>
#include <hip/hip_fp16.h>
#include <hip/hip_cooperative_groups.h>

namespace cg = cooperative_groups;

#define N_NODES 100000
#define N_EDGES 1600000
#define MSG 16
#define HID 16
#define NC 32
#define PREP_N 800000       // N*HID/2 packed half2 words == N*MSG/2 m2 words
#define A2_WORDS 1024       // NT*MSG*HID/2 packed half2 words (4 KB)

typedef _Float16 v2h __attribute__((ext_vector_type(2)));

union H2U {
    v2h h;
    unsigned int u;
};

__device__ __forceinline__ float dot2acc(unsigned int a, unsigned int b, float acc) {
    H2U x, y;
    x.u = a; y.u = b;
#if __has_builtin(__builtin_amdgcn_fdot2)
    return __builtin_amdgcn_fdot2(x.h, y.h, acc, false);
#else
    return acc + (float)x.h[0] * (float)y.h[0] + (float)x.h[1] * (float)y.h[1];
#endif
}

__device__ __forceinline__ float fast_sigmoid(float x) {
    return 1.f / (1.f + __expf(-x));
}
__device__ __forceinline__ float fast_tanh(float x) {
    return 2.f / (1.f + __expf(-2.f * x)) - 1.f;
}

// ---------------------------------------------------------------------------
// Phase: prep (grid-stride). feat f32 -> packed fp16 mirror; zero m2;
// pack edge_table to fp16.
// ---------------------------------------------------------------------------
__device__ __forceinline__ void phase_prep(
    int gtid, int gsz,
    const float* __restrict__ feat,
    const float* __restrict__ edge_table,
    unsigned int* __restrict__ feat16,
    unsigned int* __restrict__ m2,
    unsigned int* __restrict__ A2) {
    for (int i = gtid; i < PREP_N; i += gsz) {
        float2 f = reinterpret_cast<const float2*>(feat)[i];
        H2U p;
        p.h[0] = (_Float16)f.x;
        p.h[1] = (_Float16)f.y;
        feat16[i] = p.u;
        m2[i] = 0u;
    }
    for (int i = gtid; i < A2_WORDS; i += gsz) {
        float2 f = reinterpret_cast<const float2*>(edge_table)[i];
        H2U p;
        p.h[0] = (_Float16)f.x;
        p.h[1] = (_Float16)f.y;
        A2[i] = p.u;
    }
}

// ---------------------------------------------------------------------------
// Phase: edge scatter (grid-stride). 8 lanes per edge, lane c computes the
// message pair (2c,2c+1) via v_dot2_f32_f16 from the 3.2 MB L2-resident
// fp16 mirror and the 4 KB A2 table. One fire-and-forget packed-f16 atomic
// per lane into the 3.2 MB m2 (R=1: small footprint is essential -- the
// R=8 replica experiment exploded traffic 20x). Proven 153 G atomics/s.
// ---------------------------------------------------------------------------
__device__ __forceinline__ void phase_edge(
    long long gtid, long long gsz,
    const int* __restrict__ src,
    const int* __restrict__ dst,
    const int* __restrict__ etype,
    const unsigned int* __restrict__ feat16,
    const unsigned int* __restrict__ A2,
    unsigned int* __restrict__ m2) {
    const long long total = (long long)N_EDGES * 8;
    for (long long t = gtid; t < total; t += gsz) {
        int e = (int)(t >> 3);
        int c = (int)(t & 7);

        int s = src[e];
        int ty = etype[e];
        const uint4* hp = reinterpret_cast<const uint4*>(feat16 + (size_t)s * 8);
        uint4 h0 = hp[0], h1 = hp[1];
        const uint4* ap = reinterpret_cast<const uint4*>(A2 + ty * 128 + c * 16);
        uint4 a0 = ap[0], a1 = ap[1], a2 = ap[2], a3 = ap[3];

        float r0 = 0.f, r1 = 0.f;
        r0 = dot2acc(h0.x, a0.x, r0); r0 = dot2acc(h0.y, a0.y, r0);
        r0 = dot2acc(h0.z, a0.z, r0); r0 = dot2acc(h0.w, a0.w, r0);
        r0 = dot2acc(h1.x, a1.x, r0); r0 = dot2acc(h1.y, a1.y, r0);
        r0 = dot2acc(h1.z, a1.z, r0); r0 = dot2acc(h1.w, a1.w, r0);
        r1 = dot2acc(h0.x, a2.x, r1); r1 = dot2acc(h0.y, a2.y, r1);
        r1 = dot2acc(h0.z, a2.z, r1); r1 = dot2acc(h0.w, a2.w, r1);
        r1 = dot2acc(h1.x, a3.x, r1); r1 = dot2acc(h1.y, a3.y, r1);
        r1 = dot2acc(h1.z, a3.z, r1); r1 = dot2acc(h1.w, a3.w, r1);

        int d = dst[e];
        H2U p;
        p.h[0] = (_Float16)r0;
        p.h[1] = (_Float16)r1;
#if __has_builtin(__builtin_amdgcn_global_atomic_fadd_v2f16)
        __builtin_amdgcn_global_atomic_fadd_v2f16(
            reinterpret_cast<v2h*>(m2 + (size_t)d * 8 + c), p.h);
#endif
    }
}

// ---------------------------------------------------------------------------
// Phase: node (grid-stride). GRU cell + output projection. One thread per
// node; weights are wave-uniform -> scalar loads. (Proven.)
// ---------------------------------------------------------------------------
__device__ __forceinline__ void phase_node(
    int gtid, int gsz,
    const float* __restrict__ feat,
    const unsigned int* __restrict__ m2,
    const float* __restrict__ W_ih,
    const float* __restrict__ W_hh,
    const float* __restrict__ b_ih,
    const float* __restrict__ b_hh,
    const float* __restrict__ W_out,
    const float* __restrict__ b_out,
    float* __restrict__ out) {
    for (int n = gtid; n < N_NODES; n += gsz) {
        float mv[MSG], h[HID];
        {
            const uint4* mu = reinterpret_cast<const uint4*>(m2 + (size_t)n * 8);
            uint4 a = mu[0], b = mu[1];
            unsigned int w[8] = {a.x, a.y, a.z, a.w, b.x, b.y, b.z, b.w};
            #pragma unroll
            for (int i = 0; i < 8; ++i) {
                H2U hh;
                hh.u = w[i];
                mv[2 * i]     = (float)hh.h[0];
                mv[2 * i + 1] = (float)hh.h[1];
            }
            const float4* f4 = reinterpret_cast<const float4*>(feat + (size_t)n * HID);
            #pragma unroll
            for (int q = 0; q < 4; ++q) {
                float4 v = f4[q];
                h[q * 4 + 0] = v.x; h[q * 4 + 1] = v.y;
                h[q * 4 + 2] = v.z; h[q * 4 + 3] = v.w;
            }
        }

        float srz[2 * HID];
        for (int g = 0; g < 2 * HID; ++g) {
            float ai = 0.f, ah = 0.f;
            const float* wi = W_ih + g * MSG;
            const float* wh = W_hh + g * HID;
            #pragma unroll
            for (int k = 0; k < HID; ++k) {
                ai += wi[k] * mv[k];
                ah += wh[k] * h[k];
            }
            srz[g] = ai + ah + b_ih[g] + b_hh[g];
        }
        float i_n[HID], h_n[HID];
        #pragma unroll
        for (int j = 0; j < HID; ++j) {
            int g = 2 * HID + j;
            float ai = b_ih[g], ah = b_hh[g];
            const float* wi = W_ih + g * MSG;
            const float* wh = W_hh + g * HID;
            #pragma unroll
            for (int k = 0; k < HID; ++k) {
                ai += wi[k] * mv[k];
                ah += wh[k] * h[k];
            }
            i_n[j] = ai;
            h_n[j] = ah;
        }

        float hn[HID];
        #pragma unroll
        for (int j = 0; j < HID; ++j) {
            float r = fast_sigmoid(srz[j]);
            float z = fast_sigmoid(srz[HID + j]);
            float nn = fast_tanh(i_n[j] + r * h_n[j]);
            hn[j] = (1.f - z) * nn + z * h[j];
        }

        float4* op = reinterpret_cast<float4*>(out + (size_t)n * NC);
        #pragma unroll
        for (int c4 = 0; c4 < NC / 4; ++c4) {
            float4 o;
            float* oo = &o.x;
            #pragma unroll
            for (int cc = 0; cc < 4; ++cc) {
                int c = c4 * 4 + cc;
                float acc = b_out[c];
                const float* wo = W_out + c * HID;
                #pragma unroll
                for (int k = 0; k < HID; ++k) acc += wo[k] * hn[k];
                oo[cc] = acc;
            }
            op[c4] = o;
        }
    }
}

// ---------------------------------------------------------------------------
// Fused cooperative kernel: prep -> edge -> node, ONE dispatch.
// All three phases are low-pressure (no LDS, max ~112 VGPR from node), so
// fusion does not tax occupancy -- unlike the failed round-2 (R=8 traffic)
// and round-4 (256-VGPR/54KB-LDS coupling) fusions. Single-dispatch saves
// ~70 us of inter-dispatch overhead (~35 us per eliminated launch).
// ---------------------------------------------------------------------------
__global__ __launch_bounds__(256) void ggnn_fused(
    const float* feat, const int* src, const int* dst, const int* etype,
    const float* edge_table,
    const float* W_ih, const float* W_hh, const float* b_ih, const float* b_hh,
    const float* W_out, const float* b_out,
    float* out, unsigned int* m2, unsigned int* feat16, unsigned int* A2) {
    cg::grid_group grid = cg::this_grid();
    int gtid = blockIdx.x * 256 + threadIdx.x;
    int gsz = gridDim.x * 256;

    phase_prep(gtid, gsz, feat, edge_table, feat16, m2, A2);
    __threadfence();
    grid.sync();

    phase_edge((long long)gtid, (long long)gsz, src, dst, etype, feat16, A2, m2);
    __threadfence();
    grid.sync();

    phase_node(gtid, gsz, feat, m2, W_ih, W_hh, b_ih, b_hh, W_out, b_out, out);
}

// ---------------------------------------------------------------------------
// Standalone kernels: exact round-0 3-launch path (verified 200 us) as the
// fallback when cooperative launch is unavailable.
// ---------------------------------------------------------------------------
__global__ __launch_bounds__(256) void ggnn_prep_s(
    const float* feat, const float* edge_table,
    unsigned int* feat16, unsigned int* m2, unsigned int* A2) {
    phase_prep(blockIdx.x * 256 + threadIdx.x, gridDim.x * 256,
               feat, edge_table, feat16, m2, A2);
}

__global__ __launch_bounds__(256) void ggnn_edge_s(
    const int* src, const int* dst, const int* etype,
    const unsigned int* feat16, const unsigned int* A2, unsigned int* m2) {
    phase_edge((long long)(blockIdx.x * 256 + threadIdx.x),
               (long long)gridDim.x * 256, src, dst, etype, feat16, A2, m2);
}

__global__ __launch_bounds__(256) void ggnn_node_s(
    const float* feat, const unsigned int* m2,
    const float* W_ih, const float* W_hh, const float* b_ih, const float* b_hh,
    const float* W_out, const float* b_out, float* out) {
    phase_node(blockIdx.x * 256 + threadIdx.x, gridDim.x * 256,
               feat, m2, W_ih, W_hh, b_ih, b_hh, W_out, b_out, out);
}

extern "C" void kernel_launch(void* const* d_in, const int* in_sizes, int n_in,
                              void* d_out, int out_size, void* d_ws, size_t ws_size,
                              hipStream_t stream) {
    const float* feat       = (const float*)d_in[0];
    const int*   src        = (const int*)d_in[1];
    const int*   dst        = (const int*)d_in[2];
    const int*   etype      = (const int*)d_in[3];
    const float* edge_table = (const float*)d_in[4];
    const float* W_ih       = (const float*)d_in[5];
    const float* W_hh       = (const float*)d_in[6];
    const float* b_ih       = (const float*)d_in[7];
    const float* b_hh       = (const float*)d_in[8];
    const float* W_out      = (const float*)d_in[9];
    const float* b_out      = (const float*)d_in[10];
    float* out = (float*)d_out;

    // workspace layout (words): m2 [800K], feat16 [800K], A2 [1K] -> 6.4 MB
    unsigned int* m2     = (unsigned int*)d_ws;
    unsigned int* feat16 = m2 + PREP_N;
    unsigned int* A2     = feat16 + PREP_N;

    // One-time occupancy/CU query for the cooperative grid.
    static int coopBlocks = -2;   // -2 = not yet queried, -1 = unavailable
    if (coopBlocks == -2) {
        int maxB = 0;
        hipError_t oe = hipOccupancyMaxActiveBlocksPerMultiprocessor(
            &maxB, ggnn_fused, 256, 0);
        int cus = 256;
        hipDeviceProp_t prop;
        if (hipGetDeviceProperties(&prop, 0) == hipSuccess &&
            prop.multiProcessorCount > 0)
            cus = prop.multiProcessorCount;
        if (oe == hipSuccess && maxB > 0) {
            if (maxB > 8) maxB = 8;
            coopBlocks = maxB * cus;
        } else {
            coopBlocks = -1;
        }
    }

    if (coopBlocks > 0) {
        void* args[] = {
            (void*)&feat, (void*)&src, (void*)&dst, (void*)&etype,
            (void*)&edge_table,
            (void*)&W_ih, (void*)&W_hh, (void*)&b_ih, (void*)&b_hh,
            (void*)&W_out, (void*)&b_out,
            (void*)&out, (void*)&m2, (void*)&feat16, (void*)&A2
        };
        hipError_t le = hipLaunchCooperativeKernel(
            reinterpret_cast<const void*>(ggnn_fused),
            dim3((unsigned)coopBlocks), dim3(256), args, 0, stream);
        if (le == hipSuccess) return;
        coopBlocks = -1;   // remember failure, fall through
    }

    // Fallback: exact round-0 3-launch path (verified 200 us).
    int pblocks = (PREP_N + 255) / 256;                  // 3125
    ggnn_prep_s<<<pblocks, 256, 0, stream>>>(feat, edge_table, feat16, m2, A2);

    long long ethreads = (long long)N_EDGES * 8;         // 12.8M
    int eblocks = (int)((ethreads + 255) / 256);         // 50000
    ggnn_edge_s<<<eblocks, 256, 0, stream>>>(src, dst, etype, feat16, A2, m2);

    int nblocks = (N_NODES + 255) / 256;                 // 391
    ggnn_node_s<<<nblocks, 256, 0, stream>>>(feat, m2, W_ih, W_hh, b_ih, b_hh,
                                             W_out, b_out, out);
}